// Round 9
// baseline (341.180 us; speedup 1.0000x reference)
//
#include <hip/hip_runtime.h>
#include <hip/hip_bf16.h>

#define N_NODES 50000
#define N_EDGES 800000
#define D_IN    128
#define D_H     64
#define SZ_C    4
#define D_ALL   (SZ_C * D_H)   // 256

typedef __bf16 bf16x8 __attribute__((ext_vector_type(8)));
typedef __bf16 bf16x2 __attribute__((ext_vector_type(2)));
typedef float  f32x4  __attribute__((ext_vector_type(4)));
typedef unsigned short us8 __attribute__((ext_vector_type(8)));

#if defined(__has_builtin)
#if __has_builtin(__builtin_amdgcn_fdot2_f32_bf16)
#define HAVE_DOT2 1
#else
#define HAVE_DOT2 0
#endif
#else
#define HAVE_DOT2 0
#endif

__device__ __forceinline__ float bf2f(unsigned short u) {
    return __uint_as_float(((unsigned)u) << 16);
}
__device__ __forceinline__ unsigned short f2bf(float f) {
    unsigned u = __float_as_uint(f);
    unsigned r = (u + 0x7fffu + ((u >> 16) & 1u)) >> 16;   // round-to-nearest-even
    return (unsigned short)r;
}

// acc += a.lo*c.lo + a.hi*c.hi, bf16 pairs in u32, f32 accumulate
__device__ __forceinline__ float dot2bf(unsigned ab, unsigned cc, float acc) {
#if HAVE_DOT2
    return __builtin_amdgcn_fdot2_f32_bf16(__builtin_bit_cast(bf16x2, ab),
                                           __builtin_bit_cast(bf16x2, cc), acc, false);
#else
    float a0 = __uint_as_float(ab << 16);
    float a1 = __uint_as_float(ab & 0xffff0000u);
    float c0 = __uint_as_float(cc << 16);
    float c1 = __uint_as_float(cc & 0xffff0000u);
    return acc + a0 * c0 + a1 * c1;
#endif
}

// ---------------- setup kernels ----------------

// x->bf16 conversion + deg/cursor init. deg starts at 1 (self-loop slot;
// matches reference deg = in_deg + 1).
__global__ void init_f2bf_kernel(const float* __restrict__ x, unsigned short* __restrict__ x_bf,
                                 int n4, int* __restrict__ deg_cnt, int* __restrict__ cursor, int n) {
    int i = blockIdx.x * blockDim.x + threadIdx.x;
    if (i < n) { deg_cnt[i] = 1; cursor[i] = 0; }
    if (i < n4) {
        float4 v = ((const float4*)x)[i];
        ushort4 o;
        o.x = f2bf(v.x); o.y = f2bf(v.y); o.z = f2bf(v.z); o.w = f2bf(v.w);
        ((ushort4*)x_bf)[i] = o;
    }
}

__global__ void hist_kernel(const int* __restrict__ dst, int* __restrict__ deg_cnt, int e) {
    int i = blockIdx.x * blockDim.x + threadIdx.x;
    if (i < e) atomicAdd(&deg_cnt[dst[i]], 1);
}

// scan phase 1 over padlen=(deg+7)&~7 computed inline; also emits dinv.
__global__ __launch_bounds__(1024) void scan_block_kernel(
    const int* __restrict__ deg_cnt, float* __restrict__ dinv,
    int* __restrict__ row_start, int* __restrict__ bsum, int n) {
    __shared__ int wsum[16];
    int t = threadIdx.x;
    int lane = t & 63, wv = t >> 6;
    int base = blockIdx.x * 1024;
    int v = 0;
    if (base + t < n) {
        int dg = deg_cnt[base + t];
        dinv[base + t] = rsqrtf((float)dg);
        v = (dg + 7) & ~7;
    }
    int x = v;
    #pragma unroll
    for (int off = 1; off < 64; off <<= 1) {
        int y = __shfl_up(x, off, 64);
        if (lane >= off) x += y;
    }
    if (lane == 63) wsum[wv] = x;
    __syncthreads();
    if (wv == 0 && lane < 16) {
        int ws = wsum[lane];
        #pragma unroll
        for (int off = 1; off < 16; off <<= 1) {
            int y = __shfl_up(ws, off, 64);
            if (lane >= off) ws += y;
        }
        wsum[lane] = ws;
    }
    __syncthreads();
    int wbase = (wv == 0) ? 0 : wsum[wv - 1];
    int incl = x + wbase;
    if (base + t < n) row_start[base + t + 1] = incl;
    if (t == 1023) bsum[blockIdx.x] = incl;
}

__global__ void scan_tot_kernel(int* __restrict__ bsum, int nb) {
    int lane = threadIdx.x;   // one wave
    int v = (lane < nb) ? bsum[lane] : 0;
    int x = v;
    #pragma unroll
    for (int off = 1; off < 64; off <<= 1) {
        int y = __shfl_up(x, off, 64);
        if (lane >= off) x += y;
    }
    if (lane < nb) bsum[lane] = x - v;   // exclusive
}

__global__ __launch_bounds__(1024) void scan_add_kernel(
    const int* __restrict__ bsum, int* __restrict__ row_start, int n) {
    int b = blockIdx.x, t = threadIdx.x;
    int i = b * 1024 + t;
    if (b == 0 && t == 0) row_start[0] = 0;
    if (i < n) row_start[i + 1] += bsum[b];
}

// One pass: scatter real edges (slots 0..deg-2 via cursor), self edge (slot deg-1),
// zero-coef padding to x8 (gathers row 0 -> L1-hot), 32 end-pad records.
__global__ void csr_fill_kernel(const int* __restrict__ src, const int* __restrict__ dst,
                                const int* __restrict__ row_start, int* __restrict__ cursor,
                                const int* __restrict__ deg_cnt, const float* __restrict__ dinv,
                                int2* __restrict__ csr_ec) {
    int i = blockIdx.x * blockDim.x + threadIdx.x;
    if (i < N_EDGES) {
        int d = dst[i];
        int s = src[i];
        int pos = row_start[d] + atomicAdd(&cursor[d], 1);
        int2 rec;
        rec.x = s;
        rec.y = (int)(unsigned)f2bf(dinv[s] * dinv[d]);
        csr_ec[pos] = rec;
    }
    if (i < N_NODES) {
        int s = row_start[i], e = row_start[i + 1];
        int selfslot = s + deg_cnt[i] - 1;
        float dv = dinv[i];
        int2 rec;
        rec.x = i;
        rec.y = (int)(unsigned)f2bf(dv * dv);
        csr_ec[selfslot] = rec;
        rec.x = 0;
        rec.y = 0;
        for (int k = selfslot + 1; k < e; ++k) csr_ec[k] = rec;
    }
    if (i < 32) {
        int2 z0; z0.x = 0; z0.y = 0;
        csr_ec[row_start[N_NODES] + i] = z0;
    }
}

// Pack all three weight tensors into MFMA B-frag layout; blockIdx.y selects tensor.
__global__ void pack_all_kernel(const float* __restrict__ W0, const float* __restrict__ Wl,
                                unsigned short* __restrict__ W0p,
                                unsigned short* __restrict__ Wl0p,
                                unsigned short* __restrict__ Wl1p) {
    int tid = blockIdx.x * blockDim.x + threadIdx.x;
    int which = blockIdx.y;
    const float* W;
    unsigned short* P;
    int ksteps, total, chanStride;
    if (which == 0)      { W = W0;             P = W0p;  ksteps = 4; total = SZ_C * 4 * 4 * 512; chanStride = D_IN * D_H; }
    else if (which == 1) { W = Wl;             P = Wl0p; ksteps = 2; total = SZ_C * 2 * 4 * 512; chanStride = 2 * D_H * D_H; }
    else                 { W = Wl + D_H * D_H; P = Wl1p; ksteps = 2; total = SZ_C * 2 * 4 * 512; chanStride = 2 * D_H * D_H; }
    if (tid >= total) return;
    int j = tid & 7;
    int lane = (tid >> 3) & 63;
    int nn = (tid >> 9) & 3;
    int cks = tid >> 11;
    int ks = cks % ksteps;
    int c = cks / ksteps;
    int k = ks * 32 + (lane >> 4) * 8 + j;
    int d = nn * 16 + (lane & 15);
    P[tid] = f2bf(W[(size_t)c * chanStride + (size_t)k * 64 + d]);
}

// ---------------- fused layer: agg -> LDS -> MFMA -> epilogue ----------------
// Block = 256 threads = 4 waves = 64 nodes. Agg: wave w aggregates nodes
// w, w+4, ..., w+60 (pipelined 16-edge loop, x8-padded rows) into LDS z-tile
// [64][RS] (+8 elem pad -> <=2-way bank conflict, free). Then wave w = channel w
// computes the 64x64 MFMA block + bias + relu-residual; LAYER==2 adds LayerNorm.

template<int LAYER>   // 0: x[N,128]->h, 1: h->h, 2: h->LN->out
__global__ __launch_bounds__(256) void fused_layer_kernel(
    const unsigned short* __restrict__ hin,   // bf16 [N, RS]
    const int* __restrict__ row_start,
    const int2* __restrict__ csr_ec,
    const unsigned short* __restrict__ Bpack,
    const float* __restrict__ bias, int biasChanStride,
    unsigned short* __restrict__ hout,        // bf16 [N,256] (LAYER<2)
    float* __restrict__ outF, const float* __restrict__ gamma, const float* __restrict__ beta)
{
    constexpr int RS      = (LAYER == 0) ? D_IN : D_ALL;
    constexpr int KSTEPS  = (LAYER == 0) ? 4 : 2;
    constexpr int LSTRIDE = RS + 8;          // bf16 elems; 136 / 264
    constexpr int LPR = RS / 8;              // lanes per row: 16 or 32
    constexpr int G = 64 / LPR;              // edge-pair groups: 4 or 2
    constexpr int SLOTS = 16 / (2 * G);      // record-pair slots / 16-edge iter
    constexpr int TSLOTS = SLOTS / 2;        // slots in 8-edge tail
    __shared__ unsigned short zls[64 * LSTRIDE];

    int w = threadIdx.x >> 6, lane = threadIdx.x & 63;
    int g = lane / LPR, sl = lane % LPR;
    const unsigned short* hb = hin + sl * 8;
    int base = blockIdx.x * 64;

    // ---- agg phase ----
    for (int t = 0; t < 16; ++t) {
        int li = w + t * 4;
        int i = base + li;
        float acc[8] = {};
        if (i < N_NODES) {
            int s = row_start[i], e = row_start[i + 1];
            int len = e - s;                 // multiple of 8
            int nfull = len >> 4;
            bool tail = (len & 8) != 0;
            int4 r[SLOTS];
            #pragma unroll
            for (int u = 0; u < SLOTS; ++u)
                r[u] = *(const int4*)(csr_ec + s + u * (2 * G) + 2 * g);
            int j0 = s;
            for (int it = 0; it < nfull; ++it, j0 += 16) {
                uint4 row0[SLOTS], row1[SLOTS];
                #pragma unroll
                for (int u = 0; u < SLOTS; ++u) {
                    row0[u] = *(const uint4*)(hb + (size_t)r[u].x * RS);
                    row1[u] = *(const uint4*)(hb + (size_t)r[u].z * RS);
                }
                int4 rn[SLOTS];
                #pragma unroll
                for (int u = 0; u < SLOTS; ++u)
                    rn[u] = *(const int4*)(csr_ec + (j0 + 16) + u * (2 * G) + 2 * g);
                #pragma unroll
                for (int u = 0; u < SLOTS; ++u) {
                    unsigned cc = __builtin_amdgcn_perm((unsigned)r[u].y, (unsigned)r[u].w, 0x01000504u);
                    const unsigned* p0 = (const unsigned*)&row0[u];
                    const unsigned* p1 = (const unsigned*)&row1[u];
                    #pragma unroll
                    for (int q = 0; q < 4; ++q) {
                        unsigned lo = __builtin_amdgcn_perm(p0[q], p1[q], 0x01000504u);
                        unsigned hi = __builtin_amdgcn_perm(p0[q], p1[q], 0x03020706u);
                        acc[2*q]   = dot2bf(lo, cc, acc[2*q]);
                        acc[2*q+1] = dot2bf(hi, cc, acc[2*q+1]);
                    }
                }
                #pragma unroll
                for (int u = 0; u < SLOTS; ++u) r[u] = rn[u];
            }
            if (tail) {
                uint4 row0[TSLOTS], row1[TSLOTS];
                #pragma unroll
                for (int u = 0; u < TSLOTS; ++u) {
                    row0[u] = *(const uint4*)(hb + (size_t)r[u].x * RS);
                    row1[u] = *(const uint4*)(hb + (size_t)r[u].z * RS);
                }
                #pragma unroll
                for (int u = 0; u < TSLOTS; ++u) {
                    unsigned cc = __builtin_amdgcn_perm((unsigned)r[u].y, (unsigned)r[u].w, 0x01000504u);
                    const unsigned* p0 = (const unsigned*)&row0[u];
                    const unsigned* p1 = (const unsigned*)&row1[u];
                    #pragma unroll
                    for (int q = 0; q < 4; ++q) {
                        unsigned lo = __builtin_amdgcn_perm(p0[q], p1[q], 0x01000504u);
                        unsigned hi = __builtin_amdgcn_perm(p0[q], p1[q], 0x03020706u);
                        acc[2*q]   = dot2bf(lo, cc, acc[2*q]);
                        acc[2*q+1] = dot2bf(hi, cc, acc[2*q+1]);
                    }
                }
            }
        }
        #pragma unroll
        for (int off = LPR; off < 64; off <<= 1)
            #pragma unroll
            for (int q = 0; q < 8; ++q)
                acc[q] += __shfl_xor(acc[q], off, 64);
        if (g == 0) {
            us8 o;
            #pragma unroll
            for (int q = 0; q < 8; ++q) o[q] = f2bf(acc[q]);
            *(us8*)(zls + li * LSTRIDE + sl * 8) = o;
        }
    }
    __syncthreads();

    // ---- MFMA phase: wave w = channel w ----
    int c = w;
    int col = lane & 15;
    int acolbase = (LAYER == 0) ? 0 : c * 64;
    const unsigned short* Bp = Bpack + ((size_t)c * KSTEPS * 4) * 512 + (size_t)lane * 8;
    f32x4 acc4[4][4] = {};
    #pragma unroll
    for (int m = 0; m < 4; ++m) {
        #pragma unroll
        for (int ks = 0; ks < KSTEPS; ++ks) {
            const unsigned short* ap = zls + (m * 16 + (lane & 15)) * LSTRIDE
                                       + acolbase + ks * 32 + (lane >> 4) * 8;
            bf16x8 af = *(const bf16x8*)ap;
            #pragma unroll
            for (int n = 0; n < 4; ++n) {
                bf16x8 bfr = *(const bf16x8*)(Bp + (size_t)ks * 2048 + n * 512);
                acc4[m][n] = __builtin_amdgcn_mfma_f32_16x16x32_bf16(af, bfr, acc4[m][n], 0, 0, 0);
            }
        }
    }
    #pragma unroll
    for (int m = 0; m < 4; ++m) {
        int rbase = base + m * 16 + (lane >> 4) * 4;
        float hv[4][4];
        #pragma unroll
        for (int n = 0; n < 4; ++n) {
            float bv = bias[c * biasChanStride + n * 16 + col];
            #pragma unroll
            for (int r = 0; r < 4; ++r) {
                float a = acc4[m][n][r] + bv;
                hv[n][r] = (a > 0.f) ? a + a : a;   // relu(a) + a
            }
        }
        if (LAYER < 2) {
            #pragma unroll
            for (int n = 0; n < 4; ++n) {
                #pragma unroll
                for (int r = 0; r < 4; ++r) {
                    int rr = rbase + r;
                    if (rr < N_NODES)
                        hout[(size_t)rr * D_ALL + c * 64 + n * 16 + col] = f2bf(hv[n][r]);
                }
            }
        } else {
            float sum[4], sq[4];
            #pragma unroll
            for (int r = 0; r < 4; ++r) {
                sum[r] = hv[0][r] + hv[1][r] + hv[2][r] + hv[3][r];
                sq[r] = hv[0][r]*hv[0][r] + hv[1][r]*hv[1][r] + hv[2][r]*hv[2][r] + hv[3][r]*hv[3][r];
            }
            #pragma unroll
            for (int off = 1; off < 16; off <<= 1) {
                #pragma unroll
                for (int r = 0; r < 4; ++r) {
                    sum[r] += __shfl_xor(sum[r], off, 64);
                    sq[r]  += __shfl_xor(sq[r], off, 64);
                }
            }
            #pragma unroll
            for (int n = 0; n < 4; ++n) {
                float gv = gamma[n * 16 + col];
                float bv2 = beta[n * 16 + col];
                #pragma unroll
                for (int r = 0; r < 4; ++r) {
                    float mu = sum[r] * (1.f / 64.f);
                    float var = sq[r] * (1.f / 64.f) - mu * mu;
                    float rinv = rsqrtf(var + 1e-6f);
                    int rr = rbase + r;
                    if (rr < N_NODES)
                        outF[(size_t)c * N_NODES * D_H + (size_t)rr * D_H + n * 16 + col] =
                            (hv[n][r] - mu) * rinv * gv + bv2;
                }
            }
        }
    }
}

// ---------------- launch ----------------

extern "C" void kernel_launch(void* const* d_in, const int* in_sizes, int n_in,
                              void* d_out, int out_size, void* d_ws, size_t ws_size,
                              hipStream_t stream) {
    const float* x     = (const float*)d_in[0];
    const int*   edge  = (const int*)d_in[1];
    const float* W0    = (const float*)d_in[3];
    const float* b0    = (const float*)d_in[4];
    const float* Wl    = (const float*)d_in[5];
    const float* bl    = (const float*)d_in[6];
    const float* gamma = (const float*)d_in[7];
    const float* beta  = (const float*)d_in[8];
    float* out = (float*)d_out;

    const int* e_src = edge;            // edge[0]
    const int* e_dst = edge + N_EDGES;  // edge[1]

    char* ws = (char*)d_ws;
    size_t off = 0;
    auto alloc = [&](size_t bytes) -> void* {
        void* p = ws + off;
        off = (off + bytes + 255) & ~(size_t)255;
        return p;
    };
    const int NE_MAX = N_EDGES + 8 * N_NODES + 32;   // x8-padded rows + end pad
    const int NB_SCAN = (N_NODES + 1023) / 1024;     // 49
    int*   deg_cnt   = (int*)  alloc(sizeof(int)   * N_NODES);
    int*   cursor    = (int*)  alloc(sizeof(int)   * N_NODES);
    int*   row_start = (int*)  alloc(sizeof(int)   * (N_NODES + 1));
    int*   bsum      = (int*)  alloc(sizeof(int)   * 64);
    float* dinv      = (float*)alloc(sizeof(float) * N_NODES);
    int2*  csr_ec    = (int2*) alloc(sizeof(int2)  * NE_MAX);
    unsigned short* x_bf  = (unsigned short*)alloc(sizeof(unsigned short) * (size_t)N_NODES * D_IN);
    unsigned short* W0p   = (unsigned short*)alloc(sizeof(unsigned short) * SZ_C * 4 * 4 * 512);
    unsigned short* Wl0p  = (unsigned short*)alloc(sizeof(unsigned short) * SZ_C * 2 * 4 * 512);
    unsigned short* Wl1p  = (unsigned short*)alloc(sizeof(unsigned short) * SZ_C * 2 * 4 * 512);
    unsigned short* h1    = (unsigned short*)alloc(sizeof(unsigned short) * (size_t)N_NODES * D_ALL);
    unsigned short* h2    = (unsigned short*)alloc(sizeof(unsigned short) * (size_t)N_NODES * D_ALL);

    const int nb_e = (N_EDGES + 255) / 256;
    const int n4   = N_NODES * D_IN / 4;             // 1.6M

    init_f2bf_kernel<<<(n4 + 255) / 256, 256, 0, stream>>>(x, x_bf, n4, deg_cnt, cursor, N_NODES);
    hist_kernel<<<nb_e, 256, 0, stream>>>(e_dst, deg_cnt, N_EDGES);
    scan_block_kernel<<<NB_SCAN, 1024, 0, stream>>>(deg_cnt, dinv, row_start, bsum, N_NODES);
    scan_tot_kernel<<<1, 64, 0, stream>>>(bsum, NB_SCAN);
    scan_add_kernel<<<NB_SCAN, 1024, 0, stream>>>(bsum, row_start, N_NODES);
    csr_fill_kernel<<<nb_e, 256, 0, stream>>>(e_src, e_dst, row_start, cursor,
                                              deg_cnt, dinv, csr_ec);
    {
        dim3 pgrid((SZ_C * 4 * 4 * 512 + 255) / 256, 3);
        pack_all_kernel<<<pgrid, 256, 0, stream>>>(W0, Wl, W0p, Wl0p, Wl1p);
    }

    const int fgrid = (N_NODES + 63) / 64;   // 782

    // layer 0: h1 = relures(agg(x) @ W0 + b0)
    fused_layer_kernel<0><<<fgrid, 256, 0, stream>>>(x_bf, row_start, csr_ec, W0p,
                                                     b0, 64, h1, nullptr, nullptr, nullptr);
    // layer 1: h2 = relures(agg(h1) @ Wl0 + bl0)
    fused_layer_kernel<1><<<fgrid, 256, 0, stream>>>(h1, row_start, csr_ec, Wl0p,
                                                     bl, 2 * 64, h2, nullptr, nullptr, nullptr);
    // layer 2: out = LN(relures(agg(h2) @ Wl1 + bl1))
    fused_layer_kernel<2><<<fgrid, 256, 0, stream>>>(h2, row_start, csr_ec, Wl1p,
                                                     bl + 64, 2 * 64, nullptr, out, gamma, beta);
}